// Round 3
// baseline (98.480 us; speedup 1.0000x reference)
//
#include <hip/hip_runtime.h>

#define D_MODEL 768
#define BN 64
#define LN_EPS 1e-5f

typedef __attribute__((ext_vector_type(8))) short bf16x8;
typedef __attribute__((ext_vector_type(4))) float f32x4;

// RTNE float -> bf16 bits
static __device__ __forceinline__ unsigned short f2bf(float f) {
    unsigned int u = __float_as_uint(f);
    u = (u + 0x7FFFu + ((u >> 16) & 1u)) >> 16;
    return (unsigned short)u;
}

// Fold LayerNorm affine into the down-projection:
//   wd2[k,d] = wd[k,d] * ln_w[d]          (bf16)
//   S[k]     = sum_d wd2[k,d]             (f32)
//   bd2[k]   = b_down[k] + sum_d wd[k,d]*ln_b[d]
// down_pre[t,k] = rstd[t]*(x_bf[t,:]@wd2[k,:] - mu[t]*S[k]) + bd2[k]
__global__ void prep(const float* __restrict__ wd, const float* __restrict__ ln_w,
                     const float* __restrict__ ln_b, const float* __restrict__ b_down,
                     const float* __restrict__ wu,
                     unsigned short* __restrict__ wd2_b, unsigned short* __restrict__ wu_b,
                     float* __restrict__ S, float* __restrict__ bd2) {
    const int k = blockIdx.x;    // 0..63
    const int t = threadIdx.x;   // 0..63
    float s = 0.f, sb = 0.f;
    #pragma unroll
    for (int i = 0; i < 12; ++i) {
        const int d = t + 64 * i;
        const float w0 = wd[k * D_MODEL + d];
        const float w2 = w0 * ln_w[d];
        wd2_b[k * D_MODEL + d] = f2bf(w2);
        s  += w2;
        sb += w0 * ln_b[d];
    }
    #pragma unroll
    for (int off = 1; off < 64; off <<= 1) {
        s  += __shfl_xor(s, off);
        sb += __shfl_xor(sb, off);
    }
    if (t == 0) { S[k] = s; bd2[k] = b_down[k] + sb; }
    #pragma unroll
    for (int i = 0; i < 12; ++i) {
        const int idx = (k * 12 + i) * BN + t;
        wu_b[idx] = f2bf(wu[idx]);
    }
}

__global__ __launch_bounds__(128, 4) void adapter_kernel(
    const float* __restrict__ x,
    const unsigned short* __restrict__ wd2_b, const float* __restrict__ S,
    const float* __restrict__ bd2,
    const unsigned short* __restrict__ wu_b, const float* __restrict__ b_up,
    float* __restrict__ out)
{
    // only LDS: the 16x64 bf16 down-tile for the GEMM1->GEMM2 transpose
    __shared__ __align__(16) unsigned short sDown[16][72];   // 144B rows: 16B-aligned frags

    const int tid  = threadIdx.x;
    const int lane = tid & 63;
    const int w    = tid >> 6;       // wave 0..1 (split the 64 down-cols)
    const int kg   = lane >> 4;      // 0..3
    const int l16  = lane & 15;
    const size_t gt0 = (size_t)blockIdx.x * 16;

    // ---------- Fused: stream x -> {stats, bf16 A-frags} ; GEMM1 ----------
    const float* xrow = x + (gt0 + l16) * D_MODEL;   // lane owns row l16, kg-th 8-chunk
    const unsigned short* bp0 = wd2_b + (size_t)(w * 32 + l16) * D_MODEL + kg * 8;
    const unsigned short* bp1 = bp0 + 16 * D_MODEL;
    f32x4 acc0 = {0.f, 0.f, 0.f, 0.f}, acc1 = {0.f, 0.f, 0.f, 0.f};
    float sum = 0.f, sq = 0.f;
    #pragma unroll 6
    for (int ks = 0; ks < D_MODEL / 32; ++ks) {
        const float4 v0 = *(const float4*)(xrow + ks * 32 + kg * 8);
        const float4 v1 = *(const float4*)(xrow + ks * 32 + kg * 8 + 4);
        sum += (v0.x + v0.y) + (v0.z + v0.w) + (v1.x + v1.y) + (v1.z + v1.w);
        sq  += (v0.x*v0.x + v0.y*v0.y) + (v0.z*v0.z + v0.w*v0.w)
             + (v1.x*v1.x + v1.y*v1.y) + (v1.z*v1.z + v1.w*v1.w);
        bf16x8 a;
        a[0] = (short)f2bf(v0.x); a[1] = (short)f2bf(v0.y);
        a[2] = (short)f2bf(v0.z); a[3] = (short)f2bf(v0.w);
        a[4] = (short)f2bf(v1.x); a[5] = (short)f2bf(v1.y);
        a[6] = (short)f2bf(v1.z); a[7] = (short)f2bf(v1.w);
        const bf16x8 b0 = *(const bf16x8*)(bp0 + ks * 32);
        const bf16x8 b1 = *(const bf16x8*)(bp1 + ks * 32);
        acc0 = __builtin_amdgcn_mfma_f32_16x16x32_bf16(a, b0, acc0, 0, 0, 0);
        acc1 = __builtin_amdgcn_mfma_f32_16x16x32_bf16(a, b1, acc1, 0, 0, 0);
    }
    // full-row stats: combine the 4 kg-lanes sharing l16 (xor 16, 32 only!)
    sum += __shfl_xor(sum, 16);  sum += __shfl_xor(sum, 32);
    sq  += __shfl_xor(sq, 16);   sq  += __shfl_xor(sq, 32);
    const float mu_own = sum * (1.f / D_MODEL);
    const float rs_own = rsqrtf(sq * (1.f / D_MODEL) - mu_own * mu_own + LN_EPS);

    // epilogue: lane holds G[token=kg*4+r][col = w*32 + nt*16 + l16]
    {
        const int c0 = w * 32 + l16, c1 = c0 + 16;
        const float S0 = S[c0], S1 = S[c1];
        const float bd0 = bd2[c0], bd1 = bd2[c1];
        #pragma unroll
        for (int r = 0; r < 4; ++r) {
            const int t = kg * 4 + r;
            const float mu_t = __shfl(mu_own, t);   // lane t holds row t's stats
            const float rs_t = __shfl(rs_own, t);
            float v0 = rs_t * (acc0[r] - mu_t * S0) + bd0;
            float v1 = rs_t * (acc1[r] - mu_t * S1) + bd1;
            sDown[t][c0] = f2bf(v0 > 0.f ? v0 : 0.f);
            sDown[t][c1] = f2bf(v1 > 0.f ? v1 : 0.f);
        }
    }
    __syncthreads();   // the ONLY barrier

    // ---------- GEMM2 (swapped operands): D[outcol][token] ----------
    const bf16x8 pb0 = *(const bf16x8*)&sDown[l16][kg * 8];        // down[t=l16][k 0..31]
    const bf16x8 pb1 = *(const bf16x8*)&sDown[l16][32 + kg * 8];   // down[t=l16][k 32..63]
    const size_t rowOff = (gt0 + l16) * D_MODEL;
    #pragma unroll 4
    for (int j = 0; j < 24; ++j) {
        const int colBase = (2 * j + w) * 16;
        const unsigned short* wp = wu_b + (size_t)(colBase + l16) * BN;
        const bf16x8 a0 = *(const bf16x8*)(wp + kg * 8);           // wu[n=colBase+l16][k 0..31]
        const bf16x8 a1 = *(const bf16x8*)(wp + 32 + kg * 8);
        f32x4 acc = {0.f, 0.f, 0.f, 0.f};
        acc = __builtin_amdgcn_mfma_f32_16x16x32_bf16(a0, pb0, acc, 0, 0, 0);
        acc = __builtin_amdgcn_mfma_f32_16x16x32_bf16(a1, pb1, acc, 0, 0, 0);
        // lane holds out[token=l16][cols colBase+kg*4 .. +3] -> float4
        const int oc = colBase + kg * 4;
        const float4 bu = *(const float4*)(b_up + oc);
        const size_t idx = rowOff + oc;
        const float4 xv = *(const float4*)(x + idx);
        float4 o;
        o.x = acc[0] + bu.x + xv.x;
        o.y = acc[1] + bu.y + xv.y;
        o.z = acc[2] + bu.z + xv.z;
        o.w = acc[3] + bu.w + xv.w;
        *(float4*)(out + idx) = o;
    }
}

extern "C" void kernel_launch(void* const* d_in, const int* in_sizes, int n_in,
                              void* d_out, int out_size, void* d_ws, size_t ws_size,
                              hipStream_t stream) {
    const float* x      = (const float*)d_in[0];
    const float* ln_w   = (const float*)d_in[1];
    const float* ln_b   = (const float*)d_in[2];
    const float* w_down = (const float*)d_in[3];
    const float* b_down = (const float*)d_in[4];
    const float* w_up   = (const float*)d_in[5];
    const float* b_up   = (const float*)d_in[6];
    float* out = (float*)d_out;

    unsigned short* wd2_b = (unsigned short*)d_ws;               // 64*768 ush
    unsigned short* wu_b  = wd2_b + BN * D_MODEL;                // 768*64 ush
    float* S   = (float*)((char*)d_ws + 2 * BN * D_MODEL * sizeof(unsigned short));
    float* bd2 = S + BN;

    prep<<<BN, 64, 0, stream>>>(w_down, ln_w, ln_b, b_down, w_up, wd2_b, wu_b, S, bd2);

    const int tokens = in_sizes[0] / D_MODEL;   // 32768
    const int grid = tokens / 16;               // 2048
    adapter_kernel<<<grid, 128, 0, stream>>>(x, wd2_b, S, bd2, wu_b, b_up, out);
}